// Round 6
// baseline (572.506 us; speedup 1.0000x reference)
//
#include <hip/hip_runtime.h>
#include <hip/hip_bf16.h>

typedef __attribute__((ext_vector_type(8))) short bf16x8;
typedef __attribute__((ext_vector_type(4))) float f32x4;

__device__ __forceinline__ short f2bf(float f) {
    union { float f; unsigned u; } v; v.f = f;
    unsigned r = (v.u + 0x7FFFu + ((v.u >> 16) & 1u)) >> 16;
    return (short)r;
}
__device__ __forceinline__ float bf2f(short s) {
    union { unsigned u; float f; } v; v.u = ((unsigned)(unsigned short)s) << 16;
    return v.f;
}
__device__ __forceinline__ void gll16(const void* g, void* l) {
    __builtin_amdgcn_global_load_lds(
        (const __attribute__((address_space(1))) unsigned int*)g,
        (__attribute__((address_space(3))) unsigned int*)l, 16, 0, 0);
}

// bf16-exact mask value: bf16(-998244352) == -998244352.0f exactly.
#define MASKF (-998244352.0f)

// ---------------------------------------------------------------------------
// Fused prep: [0,6144) f32->bf16 cvt of q,k,v ; [6144,10240) weight transpose
// +cvt for Wq,Wk,Wv,Wo ; [10240,11264) mask bit-pack.
__global__ __launch_bounds__(256) void k_prep(
    const float* __restrict__ qin, const float* __restrict__ kin, const float* __restrict__ vin,
    short* __restrict__ qbf, short* __restrict__ kbf, short* __restrict__ vbf,
    const float* __restrict__ Wq, const float* __restrict__ Wk,
    const float* __restrict__ Wv, const float* __restrict__ Wo,
    short* __restrict__ WqT, short* __restrict__ WkT,
    short* __restrict__ WvT, short* __restrict__ WoT,
    const int* __restrict__ mask, unsigned* __restrict__ mb)
{
    __shared__ int sm[8192];
    const int bid = blockIdx.x, tid = threadIdx.x;
    if (bid < 6144) {
        const float* in = bid < 2048 ? qin : (bid < 4096 ? kin : vin);
        short* out = bid < 2048 ? qbf : (bid < 4096 ? kbf : vbf);
        const long i = ((long)(bid & 2047) * 256 + tid) * 8;
        float4 f0 = *reinterpret_cast<const float4*>(&in[i]);
        float4 f1 = *reinterpret_cast<const float4*>(&in[i + 4]);
        bf16x8 v;
        v[0] = f2bf(f0.x); v[1] = f2bf(f0.y); v[2] = f2bf(f0.z); v[3] = f2bf(f0.w);
        v[4] = f2bf(f1.x); v[5] = f2bf(f1.y); v[6] = f2bf(f1.z); v[7] = f2bf(f1.w);
        *reinterpret_cast<bf16x8*>(&out[i]) = v;
    } else if (bid < 10240) {
        const int t2 = bid - 6144, which = t2 >> 10, local = t2 & 1023;
        const float* W = which == 0 ? Wq : (which == 1 ? Wk : (which == 2 ? Wv : Wo));
        short* WT = which == 0 ? WqT : (which == 1 ? WkT : (which == 2 ? WvT : WoT));
        float (*t)[33] = reinterpret_cast<float(*)[33]>(sm);
        const int rb = (local >> 5) * 32, cb = (local & 31) * 32;
        const int tr = tid >> 3, tc = (tid & 7) * 4;
        const float4 v = *reinterpret_cast<const float4*>(&W[(long)(rb + tr) * 1024 + cb + tc]);
        t[tr][tc + 0] = v.x; t[tr][tc + 1] = v.y; t[tr][tc + 2] = v.z; t[tr][tc + 3] = v.w;
        __syncthreads();
        short4 o;
        o.x = f2bf(t[tc + 0][tr]); o.y = f2bf(t[tc + 1][tr]);
        o.z = f2bf(t[tc + 2][tr]); o.w = f2bf(t[tc + 3][tr]);
        *reinterpret_cast<short4*>(&WT[(long)(cb + tr) * 1024 + rb + tc]) = o;
    } else {
        const long base = (long)(bid - 10240) * 8192;
#pragma unroll
        for (int i = 0; i < 8; ++i)
            *reinterpret_cast<int4*>(&sm[i * 1024 + tid * 4]) =
                *reinterpret_cast<const int4*>(&mask[base + i * 1024 + tid * 4]);
        __syncthreads();
        unsigned wv = 0;
#pragma unroll
        for (int j = 0; j < 32; ++j) wv |= (sm[tid * 32 + j] != 0 ? 1u : 0u) << j;
        mb[base / 32 + tid] = wv;
    }
}

// ---------------------------------------------------------------------------
// Fused QKV projection GEMM (z = 0:Q, 1:K, 2:V). 128x128 tile, BK=64, gll.
__global__ __launch_bounds__(256) void k_gemm_qkv(
    const short* __restrict__ A0, const short* __restrict__ A1, const short* __restrict__ A2,
    const short* __restrict__ B0, const short* __restrict__ B1, const short* __restrict__ B2,
    const float* __restrict__ b0, const float* __restrict__ b1, const float* __restrict__ b2,
    short* __restrict__ o0, short* __restrict__ o1, short* __restrict__ o2)
{
    __shared__ short As[128 * 64];
    __shared__ short Bs[128 * 64];
    const int z = blockIdx.z;
    const short* A = z == 0 ? A0 : (z == 1 ? A1 : A2);
    const short* BT = z == 0 ? B0 : (z == 1 ? B1 : B2);
    const float* bias = z == 0 ? b0 : (z == 1 ? b1 : b2);
    short* outp = z == 0 ? o0 : (z == 1 ? o1 : o2);
    const float scale = z == 0 ? 0.125f : 1.0f;

    const int tid = threadIdx.x, w = tid >> 6, lane = tid & 63;
    const int lr = lane & 15, lg = lane >> 4;
    const int rowbase = blockIdx.y * 128, colbase = blockIdx.x * 128;
    const int wr = (w >> 1) * 64, wc = (w & 1) * 64;
    const int srow = lane >> 3, sc_ = (lane & 7) ^ srow;

    f32x4 acc[4][4] = {};

    for (int kb = 0; kb < 1024; kb += 64) {
#pragma unroll
        for (int ii = 0; ii < 4; ++ii) {
            const int rl = w * 32 + ii * 8 + srow;
            gll16(A + (long)(rowbase + rl) * 1024 + kb + sc_ * 8, &As[(w * 32 + ii * 8) * 64]);
            gll16(BT + (long)(colbase + rl) * 1024 + kb + sc_ * 8, &Bs[(w * 32 + ii * 8) * 64]);
        }
        __syncthreads();
#pragma unroll
        for (int ks = 0; ks < 2; ++ks) {
            bf16x8 a[4], bq[4];
#pragma unroll
            for (int m = 0; m < 4; ++m) {
                const int r = wr + m * 16 + lr;
                a[m] = *reinterpret_cast<const bf16x8*>(&As[r * 64 + (((ks * 4 + lg) ^ (r & 7)) << 3)]);
            }
#pragma unroll
            for (int n = 0; n < 4; ++n) {
                const int r = wc + n * 16 + lr;
                bq[n] = *reinterpret_cast<const bf16x8*>(&Bs[r * 64 + (((ks * 4 + lg) ^ (r & 7)) << 3)]);
            }
#pragma unroll
            for (int m = 0; m < 4; ++m)
#pragma unroll
                for (int n = 0; n < 4; ++n)
                    acc[m][n] = __builtin_amdgcn_mfma_f32_16x16x32_bf16(a[m], bq[n], acc[m][n], 0, 0, 0);
        }
        __syncthreads();
    }

#pragma unroll
    for (int m = 0; m < 4; ++m) {
#pragma unroll
        for (int n = 0; n < 4; ++n) {
            const int C = colbase + wc + n * 16 + lr;
            const float bv = bias[C];
#pragma unroll
            for (int rr = 0; rr < 4; ++rr) {
                const int R = rowbase + wr + m * 16 + lg * 4 + rr;
                const float val = (acc[m][n][rr] + bv) * scale;
                const int b = R >> 11, s = R & 2047, h = C >> 6, dh = C & 63;
                if (z != 2)
                    outp[(((long)(b * 16 + h) * 2048 + s) << 6) + dh] = f2bf(val);
                else
                    outp[(((long)(b * 16 + h) * 64 + dh) << 11) + s] = f2bf(val);
            }
        }
    }
}

// ---------------------------------------------------------------------------
// Out-projection GEMM: f32 out = A*WoT + bias + resid
__global__ __launch_bounds__(256) void k_gemm_o(
    const short* __restrict__ A, const short* __restrict__ BT,
    const float* __restrict__ bias, const float* __restrict__ resid,
    float* __restrict__ outp)
{
    __shared__ short As[128 * 64];
    __shared__ short Bs[128 * 64];
    const int tid = threadIdx.x, w = tid >> 6, lane = tid & 63;
    const int lr = lane & 15, lg = lane >> 4;
    const int rowbase = blockIdx.y * 128, colbase = blockIdx.x * 128;
    const int wr = (w >> 1) * 64, wc = (w & 1) * 64;
    const int srow = lane >> 3, sc_ = (lane & 7) ^ srow;

    f32x4 acc[4][4] = {};

    for (int kb = 0; kb < 1024; kb += 64) {
#pragma unroll
        for (int ii = 0; ii < 4; ++ii) {
            const int rl = w * 32 + ii * 8 + srow;
            gll16(A + (long)(rowbase + rl) * 1024 + kb + sc_ * 8, &As[(w * 32 + ii * 8) * 64]);
            gll16(BT + (long)(colbase + rl) * 1024 + kb + sc_ * 8, &Bs[(w * 32 + ii * 8) * 64]);
        }
        __syncthreads();
#pragma unroll
        for (int ks = 0; ks < 2; ++ks) {
            bf16x8 a[4], bq[4];
#pragma unroll
            for (int m = 0; m < 4; ++m) {
                const int r = wr + m * 16 + lr;
                a[m] = *reinterpret_cast<const bf16x8*>(&As[r * 64 + (((ks * 4 + lg) ^ (r & 7)) << 3)]);
            }
#pragma unroll
            for (int n = 0; n < 4; ++n) {
                const int r = wc + n * 16 + lr;
                bq[n] = *reinterpret_cast<const bf16x8*>(&Bs[r * 64 + (((ks * 4 + lg) ^ (r & 7)) << 3)]);
            }
#pragma unroll
            for (int m = 0; m < 4; ++m)
#pragma unroll
                for (int n = 0; n < 4; ++n)
                    acc[m][n] = __builtin_amdgcn_mfma_f32_16x16x32_bf16(a[m], bq[n], acc[m][n], 0, 0, 0);
        }
        __syncthreads();
    }

#pragma unroll
    for (int m = 0; m < 4; ++m) {
#pragma unroll
        for (int n = 0; n < 4; ++n) {
            const int C = colbase + wc + n * 16 + lr;
            const float bv = bias[C];
#pragma unroll
            for (int rr = 0; rr < 4; ++rr) {
                const int R = rowbase + wr + m * 16 + lg * 4 + rr;
                const long idx = (long)R * 1024 + C;
                outp[idx] = acc[m][n][rr] + bv + resid[idx];
            }
        }
    }
}

// ---------------------------------------------------------------------------
// k_score: S = masked(QK^T) as bf16 [bh][2048][2048], plus per-128-col-tile
// partial row stats (max, sum-exp) for flash-combine. K=64 -> one staged pass.
__global__ __launch_bounds__(256) void k_score(
    const short* __restrict__ qh, const short* __restrict__ kh,
    const unsigned* __restrict__ mbits, short* __restrict__ S,
    float* __restrict__ pmax, float* __restrict__ plsum)
{
    __shared__ short As[128 * 64];
    __shared__ short Bs[128 * 64];
    __shared__ float sm_[4][64];
    __shared__ float sl_[4][64];
    const int bh = blockIdx.z, b = bh >> 4;
    const int rowbase = blockIdx.y * 128, colbase = blockIdx.x * 128;
    const int tid = threadIdx.x, w = tid >> 6, lane = tid & 63;
    const int lr = lane & 15, lg = lane >> 4;
    const int wr = (w >> 1) * 64, wc = (w & 1) * 64;
    const int srow = lane >> 3, sc_ = (lane & 7) ^ srow;
    const short* A = qh + (long)bh * 131072;
    const short* BT = kh + (long)bh * 131072;
    const unsigned* mbp = mbits + (long)b * 131072;

#pragma unroll
    for (int ii = 0; ii < 4; ++ii) {
        const int rl = w * 32 + ii * 8 + srow;
        gll16(A + (long)(rowbase + rl) * 64 + sc_ * 8, &As[(w * 32 + ii * 8) * 64]);
        gll16(BT + (long)(colbase + rl) * 64 + sc_ * 8, &Bs[(w * 32 + ii * 8) * 64]);
    }
    __syncthreads();

    f32x4 acc[4][4] = {};
#pragma unroll
    for (int ks = 0; ks < 2; ++ks) {
        bf16x8 a[4], bq[4];
#pragma unroll
        for (int m = 0; m < 4; ++m) {
            const int r = wr + m * 16 + lr;
            a[m] = *reinterpret_cast<const bf16x8*>(&As[r * 64 + (((ks * 4 + lg) ^ (r & 7)) << 3)]);
        }
#pragma unroll
        for (int n = 0; n < 4; ++n) {
            const int r = wc + n * 16 + lr;
            bq[n] = *reinterpret_cast<const bf16x8*>(&Bs[r * 64 + (((ks * 4 + lg) ^ (r & 7)) << 3)]);
        }
#pragma unroll
        for (int m = 0; m < 4; ++m)
#pragma unroll
            for (int n = 0; n < 4; ++n)
                acc[m][n] = __builtin_amdgcn_mfma_f32_16x16x32_bf16(a[m], bq[n], acc[m][n], 0, 0, 0);
    }

    // epilogue: mask, store bf16 S, per-row partial stats over this wave's 64 cols
#pragma unroll
    for (int m = 0; m < 4; ++m) {
#pragma unroll
        for (int rr = 0; rr < 4; ++rr) {
            const int R = rowbase + wr + m * 16 + lg * 4 + rr;
            const unsigned mw0 = mbp[R * 64 + ((colbase + wc) >> 5)];
            const unsigned mw1 = mbp[R * 64 + ((colbase + wc) >> 5) + 1];
            float sv[4];
#pragma unroll
            for (int n = 0; n < 4; ++n) {
                const bool masked = (((n < 2) ? mw0 : mw1) >> (((n & 1) << 4) + lr)) & 1;
                sv[n] = masked ? MASKF : acc[m][n][rr];
                S[((long)bh * 2048 + R) * 2048 + colbase + wc + n * 16 + lr] = f2bf(sv[n]);
            }
            float mx = fmaxf(fmaxf(sv[0], sv[1]), fmaxf(sv[2], sv[3]));
#pragma unroll
            for (int off = 1; off < 16; off <<= 1) mx = fmaxf(mx, __shfl_xor(mx, off, 16));
            float es = __expf(sv[0] - mx) + __expf(sv[1] - mx) +
                       __expf(sv[2] - mx) + __expf(sv[3] - mx);
#pragma unroll
            for (int off = 1; off < 16; off <<= 1) es += __shfl_xor(es, off, 16);
            if (lr == 0) {
                sm_[w][m * 16 + lg * 4 + rr] = mx;
                sl_[w][m * 16 + lg * 4 + rr] = es;
            }
        }
    }
    __syncthreads();
    if (tid < 128) {
        const int R = tid, wlo = (R >> 6) * 2, ri = R & 63;
        const float m1 = sm_[wlo][ri], m2 = sm_[wlo + 1][ri];
        const float mm = fmaxf(m1, m2);
        const float ll = sl_[wlo][ri] * __expf(m1 - mm) + sl_[wlo + 1][ri] * __expf(m2 - mm);
        const long sidx = ((long)bh * 2048 + rowbase + R) * 16 + blockIdx.x;
        pmax[sidx] = mm;
        plsum[sidx] = ll;
    }
}

// ---------------------------------------------------------------------------
// k_attnout: combine partial stats -> (m, 1/l); one sweep over S: p=exp(s-m)/l,
// store attn f32 (float4, 8 rows x 256B per instr) + PV MFMA -> ctx bf16.
// Barrier-free; Ps LDS is wave-private.
__global__ __launch_bounds__(256) void k_attnout(
    const short* __restrict__ S, const float* __restrict__ pmax,
    const float* __restrict__ plsum, const short* __restrict__ vt,
    float* __restrict__ attn_out, short* __restrict__ ctxb)
{
    const int g = blockIdx.x;
    const int bh = (g & 7) * 4 + ((g >> 3) & 3);  // XCD-pinned bh groups
    const int qt = g >> 5;
    const int tid = threadIdx.x, w = tid >> 6, lane = tid & 63;
    const int lr = lane & 15, lg = lane >> 4;
    const int irow = qt * 64 + w * 16;
    const long arow = (long)bh * 2048 + irow;
    __shared__ short Ps[4][16 * 72];

    // stats: lane lr handles row irow+lr (replicated across the 4 lane-groups)
    float m_, il_;
    {
        const float4* pm4 = reinterpret_cast<const float4*>(pmax + (arow + lr) * 16);
        const float4* pl4 = reinterpret_cast<const float4*>(plsum + (arow + lr) * 16);
        const float4 a0 = pm4[0], a1 = pm4[1], a2 = pm4[2], a3 = pm4[3];
        m_ = fmaxf(fmaxf(fmaxf(a0.x, a0.y), fmaxf(a0.z, a0.w)),
                   fmaxf(fmaxf(fmaxf(a1.x, a1.y), fmaxf(a1.z, a1.w)),
                         fmaxf(fmaxf(fmaxf(a2.x, a2.y), fmaxf(a2.z, a2.w)),
                               fmaxf(fmaxf(a3.x, a3.y), fmaxf(a3.z, a3.w)))));
        const float4 b0 = pl4[0], b1 = pl4[1], b2 = pl4[2], b3 = pl4[3];
        float l = b0.x * __expf(a0.x - m_) + b0.y * __expf(a0.y - m_) +
                  b0.z * __expf(a0.z - m_) + b0.w * __expf(a0.w - m_) +
                  b1.x * __expf(a1.x - m_) + b1.y * __expf(a1.y - m_) +
                  b1.z * __expf(a1.z - m_) + b1.w * __expf(a1.w - m_) +
                  b2.x * __expf(a2.x - m_) + b2.y * __expf(a2.y - m_) +
                  b2.z * __expf(a2.z - m_) + b2.w * __expf(a2.w - m_) +
                  b3.x * __expf(a3.x - m_) + b3.y * __expf(a3.y - m_) +
                  b3.z * __expf(a3.z - m_) + b3.w * __expf(a3.w - m_);
        il_ = 1.0f / l;
    }
    const int rowA = lane >> 3, colA = (lane & 7) * 8;
    const float mA = __shfl(m_, rowA, 16),     iA = __shfl(il_, rowA, 16);
    const float mB = __shfl(m_, rowA + 8, 16), iB = __shfl(il_, rowA + 8, 16);

    const short* Sp = S + arow * 2048;
    const short* vtp = vt + (long)bh * 131072;
    f32x4 acc[4] = {};

    for (int ch = 0; ch < 32; ++ch) {
        const bf16x8 sa = *reinterpret_cast<const bf16x8*>(&Sp[(long)rowA * 2048 + ch * 64 + colA]);
        const bf16x8 sb = *reinterpret_cast<const bf16x8*>(&Sp[(long)(rowA + 8) * 2048 + ch * 64 + colA]);
        float pa[8], pb[8];
#pragma unroll
        for (int j = 0; j < 8; ++j) {
            pa[j] = __expf(bf2f(sa[j]) - mA) * iA;
            pb[j] = __expf(bf2f(sb[j]) - mB) * iB;
        }
        float* oa = &attn_out[(arow + rowA) * 2048 + ch * 64 + colA];
        float* ob = &attn_out[(arow + rowA + 8) * 2048 + ch * 64 + colA];
        *reinterpret_cast<float4*>(oa)     = make_float4(pa[0], pa[1], pa[2], pa[3]);
        *reinterpret_cast<float4*>(oa + 4) = make_float4(pa[4], pa[5], pa[6], pa[7]);
        *reinterpret_cast<float4*>(ob)     = make_float4(pb[0], pb[1], pb[2], pb[3]);
        *reinterpret_cast<float4*>(ob + 4) = make_float4(pb[4], pb[5], pb[6], pb[7]);

        bf16x8 ea, eb;
#pragma unroll
        for (int j = 0; j < 8; ++j) { ea[j] = f2bf(pa[j]); eb[j] = f2bf(pb[j]); }
        *reinterpret_cast<bf16x8*>(&Ps[w][rowA * 72 + colA]) = ea;
        *reinterpret_cast<bf16x8*>(&Ps[w][(rowA + 8) * 72 + colA]) = eb;

        const bf16x8 pa0 = *reinterpret_cast<const bf16x8*>(&Ps[w][lr * 72 + lg * 8]);
        const bf16x8 pa1 = *reinterpret_cast<const bf16x8*>(&Ps[w][lr * 72 + 32 + lg * 8]);
#pragma unroll
        for (int gi = 0; gi < 4; ++gi) {
            const bf16x8 v0 = *reinterpret_cast<const bf16x8*>(&vtp[(long)(gi * 16 + lr) * 2048 + ch * 64 + lg * 8]);
            const bf16x8 v1 = *reinterpret_cast<const bf16x8*>(&vtp[(long)(gi * 16 + lr) * 2048 + ch * 64 + 32 + lg * 8]);
            acc[gi] = __builtin_amdgcn_mfma_f32_16x16x32_bf16(pa0, v0, acc[gi], 0, 0, 0);
            acc[gi] = __builtin_amdgcn_mfma_f32_16x16x32_bf16(pa1, v1, acc[gi], 0, 0, 0);
        }
    }
#pragma unroll
    for (int gi = 0; gi < 4; ++gi)
#pragma unroll
        for (int rr = 0; rr < 4; ++rr)
            ctxb[(arow + lg * 4 + rr) * 64 + gi * 16 + lr] = f2bf(acc[gi][rr]);
}

// ---------------------------------------------------------------------------
// Fallback monolithic attention (round-4 proven path) if ws is too small.
__global__ __launch_bounds__(256, 3) void k_attn(
    const short* __restrict__ qh, const short* __restrict__ kh,
    const short* __restrict__ vt, const unsigned* __restrict__ mbits,
    float* __restrict__ attn_out, short* __restrict__ ctxb)
{
    const int g = blockIdx.x, xcd = g & 7, u = g >> 3;
    const int bh = u >> 2, qt = xcd * 4 + (u & 3);
    const int b = bh >> 4;
    const int tid = threadIdx.x, w = tid >> 6, lane = tid & 63;
    const int lr = lane & 15, lg = lane >> 4;
    const int irow = qt * 64 + w * 16;
    const long arow = (long)bh * 2048 + irow;

    __shared__ short Ks[2][64 * 64];
    __shared__ short Vs[2][64 * 64];
    __shared__ short Ps[4][16 * 72];

    const short* qhp = qh + arow * 64;
    const short* khp = kh + (long)bh * 131072;
    const short* vtp = vt + (long)bh * 131072;
    const unsigned* mbp = mbits + (long)b * 131072 + (long)irow * 64;

    const bf16x8 aq0 = *reinterpret_cast<const bf16x8*>(&qhp[lr * 64 + lg * 8]);
    const bf16x8 aq1 = *reinterpret_cast<const bf16x8*>(&qhp[lr * 64 + 32 + lg * 8]);
    const int srow = lane >> 3, sc_ = (lane & 7) ^ srow;

    auto stage_k = [&](int buf, int ch) {
#pragma unroll
        for (int ii = 0; ii < 2; ++ii) {
            const int r0 = w * 16 + ii * 8;
            gll16(khp + (long)(ch * 64 + r0 + srow) * 64 + sc_ * 8, &Ks[buf][r0 * 64]);
        }
    };
    auto stage_v = [&](int buf, int ch) {
#pragma unroll
        for (int ii = 0; ii < 2; ++ii) {
            const int r0 = w * 16 + ii * 8;
            gll16(vtp + (long)(r0 + srow) * 2048 + ch * 64 + sc_ * 8, &Vs[buf][r0 * 64]);
        }
    };
    auto kfrag = [&](int buf, int t, int ks) -> bf16x8 {
        const int r = t * 16 + lr;
        return *reinterpret_cast<const bf16x8*>(&Ks[buf][r * 64 + (((ks * 4 + lg) ^ (r & 7)) << 3)]);
    };
    auto vfrag = [&](int buf, int gi, int ks) -> bf16x8 {
        const int r = gi * 16 + lr;
        return *reinterpret_cast<const bf16x8*>(&Vs[buf][r * 64 + (((ks * 4 + lg) ^ (r & 7)) << 3)]);
    };

    float m[4], l[4];
#pragma unroll
    for (int rr = 0; rr < 4; ++rr) { m[rr] = -3.0e38f; l[rr] = 0.f; }
    f32x4 acc[4] = {};

    stage_k(0, 0); stage_v(0, 0);
    asm volatile("s_waitcnt vmcnt(0)" ::: "memory");
    __builtin_amdgcn_s_barrier();
    asm volatile("" ::: "memory");

    for (int ch = 0; ch < 32; ++ch) {
        const int cur = ch & 1;
        unsigned mw[4][2];
#pragma unroll
        for (int rr = 0; rr < 4; ++rr) {
            mw[rr][0] = mbp[(lg * 4 + rr) * 64 + ch * 2];
            mw[rr][1] = mbp[(lg * 4 + rr) * 64 + ch * 2 + 1];
        }
        asm volatile("" ::: "memory");
        if (ch < 31) { stage_k(cur ^ 1, ch + 1); stage_v(cur ^ 1, ch + 1); }
        asm volatile("" ::: "memory");

        f32x4 sct[4];
#pragma unroll
        for (int t = 0; t < 4; ++t) {
            f32x4 sc = {};
            sc = __builtin_amdgcn_mfma_f32_16x16x32_bf16(aq0, kfrag(cur, t, 0), sc, 0, 0, 0);
            sc = __builtin_amdgcn_mfma_f32_16x16x32_bf16(aq1, kfrag(cur, t, 1), sc, 0, 0, 0);
#pragma unroll
            for (int rr = 0; rr < 4; ++rr) {
                const bool masked = (mw[rr][t >> 1] >> (((t & 1) << 4) + lr)) & 1;
                sct[t][rr] = masked ? -1e9f : sc[rr];
            }
        }
        float f[4];
#pragma unroll
        for (int rr = 0; rr < 4; ++rr) {
            float c = fmaxf(fmaxf(sct[0][rr], sct[1][rr]), fmaxf(sct[2][rr], sct[3][rr]));
#pragma unroll
            for (int off = 1; off < 16; off <<= 1) c = fmaxf(c, __shfl_xor(c, off, 16));
            const bool bump = c > m[rr] + 8.0f;
            const float mn = bump ? c : m[rr];
            f[rr] = bump ? __expf(m[rr] - mn) : 1.0f;
            m[rr] = mn;
        }
        float esum[4] = {0.f, 0.f, 0.f, 0.f};
#pragma unroll
        for (int t = 0; t < 4; ++t)
#pragma unroll
            for (int rr = 0; rr < 4; ++rr) {
                const float p = __expf(sct[t][rr] - m[rr]);
                esum[rr] += p;
                Ps[w][(lg * 4 + rr) * 72 + t * 16 + lr] = f2bf(p);
            }
#pragma unroll
        for (int rr = 0; rr < 4; ++rr) l[rr] = l[rr] * f[rr] + esum[rr];
#pragma unroll
        for (int gi = 0; gi < 4; ++gi)
#pragma unroll
            for (int rr = 0; rr < 4; ++rr) acc[gi][rr] *= f[rr];

        const bf16x8 pa0 = *reinterpret_cast<const bf16x8*>(&Ps[w][lr * 72 + lg * 8]);
        const bf16x8 pa1 = *reinterpret_cast<const bf16x8*>(&Ps[w][lr * 72 + 32 + lg * 8]);
#pragma unroll
        for (int gi = 0; gi < 4; ++gi) {
            acc[gi] = __builtin_amdgcn_mfma_f32_16x16x32_bf16(pa0, vfrag(cur, gi, 0), acc[gi], 0, 0, 0);
            acc[gi] = __builtin_amdgcn_mfma_f32_16x16x32_bf16(pa1, vfrag(cur, gi, 1), acc[gi], 0, 0, 0);
        }
        asm volatile("s_waitcnt vmcnt(0)" ::: "memory");
        __builtin_amdgcn_s_barrier();
        asm volatile("" ::: "memory");
    }

    float mf[4], il[4];
#pragma unroll
    for (int rr = 0; rr < 4; ++rr) {
        float lw = l[rr];
#pragma unroll
        for (int off = 1; off < 16; off <<= 1) lw += __shfl_xor(lw, off, 16);
        il[rr] = 1.0f / lw;
        mf[rr] = m[rr];
    }
#pragma unroll
    for (int gi = 0; gi < 4; ++gi)
#pragma unroll
        for (int rr = 0; rr < 4; ++rr)
            ctxb[(arow + lg * 4 + rr) * 64 + gi * 16 + lr] = f2bf(acc[gi][rr] * il[rr]);

    stage_k(0, 0);
    asm volatile("s_waitcnt vmcnt(0)" ::: "memory");
    __builtin_amdgcn_s_barrier();
    asm volatile("" ::: "memory");

    for (int ch = 0; ch < 32; ++ch) {
        const int cur = ch & 1;
        unsigned mw[4][2];
#pragma unroll
        for (int rr = 0; rr < 4; ++rr) {
            mw[rr][0] = mbp[(lg * 4 + rr) * 64 + ch * 2];
            mw[rr][1] = mbp[(lg * 4 + rr) * 64 + ch * 2 + 1];
        }
        asm volatile("" ::: "memory");
        if (ch < 31) stage_k(cur ^ 1, ch + 1);
        asm volatile("" ::: "memory");

#pragma unroll
        for (int t = 0; t < 4; ++t) {
            f32x4 sc = {};
            sc = __builtin_amdgcn_mfma_f32_16x16x32_bf16(aq0, kfrag(cur, t, 0), sc, 0, 0, 0);
            sc = __builtin_amdgcn_mfma_f32_16x16x32_bf16(aq1, kfrag(cur, t, 1), sc, 0, 0, 0);
#pragma unroll
            for (int rr = 0; rr < 4; ++rr) {
                const bool masked = (mw[rr][t >> 1] >> (((t & 1) << 4) + lr)) & 1;
                const float s = masked ? -1e9f : sc[rr];
                const float p = __expf(s - mf[rr]) * il[rr];
                Ps[w][(lg * 4 + rr) * 72 + t * 16 + lr] = f2bf(p);
            }
        }
#pragma unroll
        for (int i2 = 0; i2 < 4; ++i2) {
            const int r = i2 * 4 + lg;
            const short4 p4 = *reinterpret_cast<const short4*>(&Ps[w][r * 72 + lr * 4]);
            float4 o;
            o.x = bf2f(p4.x); o.y = bf2f(p4.y); o.z = bf2f(p4.z); o.w = bf2f(p4.w);
            *reinterpret_cast<float4*>(&attn_out[(arow + r) * 2048 + ch * 64 + lr * 4]) = o;
        }
        asm volatile("s_waitcnt vmcnt(4)" ::: "memory");
        __builtin_amdgcn_s_barrier();
        asm volatile("" ::: "memory");
    }
}

// ---------------------------------------------------------------------------
__global__ __launch_bounds__(256) void k_ln(const float* __restrict__ x,
    const float* __restrict__ gamma, const float* __restrict__ beta,
    float* __restrict__ out)
{
    __shared__ float red[8];
    const int r = blockIdx.x, tid = threadIdx.x;
    const float4 v = reinterpret_cast<const float4*>(x + (long)r * 1024)[tid];
    float s = v.x + v.y + v.z + v.w;
    float q2 = v.x * v.x + v.y * v.y + v.z * v.z + v.w * v.w;
#pragma unroll
    for (int off = 32; off; off >>= 1) {
        s += __shfl_xor(s, off, 64);
        q2 += __shfl_xor(q2, off, 64);
    }
    if ((tid & 63) == 0) { red[(tid >> 6) * 2] = s; red[(tid >> 6) * 2 + 1] = q2; }
    __syncthreads();
    s = red[0] + red[2] + red[4] + red[6];
    q2 = red[1] + red[3] + red[5] + red[7];
    const float mu = s * (1.0f / 1024.0f);
    const float var = q2 * (1.0f / 1024.0f) - mu * mu;
    const float rs = rsqrtf(var + 1e-5f);
    const float4 gm = reinterpret_cast<const float4*>(gamma)[tid];
    const float4 bb = reinterpret_cast<const float4*>(beta)[tid];
    float4 o;
    o.x = (v.x - mu) * rs * gm.x + bb.x;
    o.y = (v.y - mu) * rs * gm.y + bb.y;
    o.z = (v.z - mu) * rs * gm.z + bb.z;
    o.w = (v.w - mu) * rs * gm.w + bb.w;
    reinterpret_cast<float4*>(out + (long)r * 1024)[tid] = o;
}

// ---------------------------------------------------------------------------
extern "C" void kernel_launch(void* const* d_in, const int* in_sizes, int n_in,
                              void* d_out, int out_size, void* d_ws, size_t ws_size,
                              hipStream_t stream)
{
    const float* qin  = (const float*)d_in[0];
    const float* kin  = (const float*)d_in[1];
    const float* vin  = (const float*)d_in[2];
    const int*   mask = (const int*)d_in[3];
    const float* Wq = (const float*)d_in[4];
    const float* bq = (const float*)d_in[5];
    const float* Wk = (const float*)d_in[6];
    const float* bk = (const float*)d_in[7];
    const float* Wv = (const float*)d_in[8];
    const float* bv = (const float*)d_in[9];
    const float* Wo = (const float*)d_in[10];
    const float* bo = (const float*)d_in[11];
    const float* gamma = (const float*)d_in[12];
    const float* beta  = (const float*)d_in[13];

    char* ws = (char*)d_ws;
    short* WqT = (short*)(ws + (0ul  << 20));
    short* WkT = (short*)(ws + (2ul  << 20));
    short* WvT = (short*)(ws + (4ul  << 20));
    short* WoT = (short*)(ws + (6ul  << 20));
    short* qh  = (short*)(ws + (8ul  << 20));
    short* khb = (short*)(ws + (16ul << 20));
    short* vtb = (short*)(ws + (24ul << 20));
    unsigned* mb = (unsigned*)(ws + (32ul << 20));
    short* ctxb = (short*)(ws + (33ul << 20));      // 8 MiB
    float* pmax  = (float*)(ws + (41ul << 20));     // 4 MiB
    float* plsum = (float*)(ws + (45ul << 20));     // 4 MiB
    short* qbf = (short*)(ws + (49ul << 20));       // dead after qkv-proj
    short* kbf = (short*)(ws + (57ul << 20));
    short* vbf = (short*)(ws + (65ul << 20));
    short* Sb  = (short*)(ws + (49ul << 20));       // 256 MiB, overlaps q/k/vbf
    float* xb  = (float*)(ws + (49ul << 20));       // 16 MiB, used after S is dead

    float* outLN = (float*)d_out;
    float* attnO = (float*)d_out + 4194304;

    const bool big = ws_size >= (305ul << 20);

    const dim3 blk(256);
    k_prep<<<dim3(11264), blk, 0, stream>>>(qin, kin, vin, qbf, kbf, vbf,
                                            Wq, Wk, Wv, Wo, WqT, WkT, WvT, WoT, mask, mb);
    k_gemm_qkv<<<dim3(8, 32, 3), blk, 0, stream>>>(qbf, kbf, vbf, WqT, WkT, WvT,
                                                   bq, bk, bv, qh, khb, vtb);
    if (big) {
        k_score<<<dim3(16, 16, 32), blk, 0, stream>>>(qh, khb, mb, Sb, pmax, plsum);
        k_attnout<<<dim3(1024), blk, 0, stream>>>(Sb, pmax, plsum, vtb, attnO, ctxb);
    } else {
        k_attn<<<dim3(1024), blk, 0, stream>>>(qh, khb, vtb, mb, attnO, ctxb);
    }
    k_gemm_o<<<dim3(8, 32), blk, 0, stream>>>(ctxb, WoT, bo, qin, xb);
    k_ln<<<dim3(4096), blk, 0, stream>>>(xb, gamma, beta, outLN);
}

// Round 7
// 384.881 us; speedup vs baseline: 1.4875x; 1.4875x over previous
//
#include <hip/hip_runtime.h>
#include <hip/hip_bf16.h>

typedef __attribute__((ext_vector_type(8))) short bf16x8;
typedef __attribute__((ext_vector_type(4))) float f32x4;

__device__ __forceinline__ short f2bf(float f) {
    union { float f; unsigned u; } v; v.f = f;
    unsigned r = (v.u + 0x7FFFu + ((v.u >> 16) & 1u)) >> 16;
    return (short)r;
}
__device__ __forceinline__ float bf2f(short s) {
    union { unsigned u; float f; } v; v.u = ((unsigned)(unsigned short)s) << 16;
    return v.f;
}
__device__ __forceinline__ void gll16(const void* g, void* l) {
    __builtin_amdgcn_global_load_lds(
        (const __attribute__((address_space(1))) unsigned int*)g,
        (__attribute__((address_space(3))) unsigned int*)l, 16, 0, 0);
}

// Q projection is pre-scaled by 0.125 * log2(e) so softmax runs in exp2 domain.
#define QSCALE 0.18033688011112042f

// ---------------------------------------------------------------------------
// Fused prep: [0,6144) f32->bf16 cvt of q,k,v ; [6144,10240) weight transpose
// +cvt for Wq,Wk,Wv,Wo ; [10240,11264) mask bit-pack.
__global__ __launch_bounds__(256) void k_prep(
    const float* __restrict__ qin, const float* __restrict__ kin, const float* __restrict__ vin,
    short* __restrict__ qbf, short* __restrict__ kbf, short* __restrict__ vbf,
    const float* __restrict__ Wq, const float* __restrict__ Wk,
    const float* __restrict__ Wv, const float* __restrict__ Wo,
    short* __restrict__ WqT, short* __restrict__ WkT,
    short* __restrict__ WvT, short* __restrict__ WoT,
    const int* __restrict__ mask, unsigned* __restrict__ mb)
{
    __shared__ int sm[8192];
    const int bid = blockIdx.x, tid = threadIdx.x;
    if (bid < 6144) {
        const float* in = bid < 2048 ? qin : (bid < 4096 ? kin : vin);
        short* out = bid < 2048 ? qbf : (bid < 4096 ? kbf : vbf);
        const long i = ((long)(bid & 2047) * 256 + tid) * 8;
        float4 f0 = *reinterpret_cast<const float4*>(&in[i]);
        float4 f1 = *reinterpret_cast<const float4*>(&in[i + 4]);
        bf16x8 v;
        v[0] = f2bf(f0.x); v[1] = f2bf(f0.y); v[2] = f2bf(f0.z); v[3] = f2bf(f0.w);
        v[4] = f2bf(f1.x); v[5] = f2bf(f1.y); v[6] = f2bf(f1.z); v[7] = f2bf(f1.w);
        *reinterpret_cast<bf16x8*>(&out[i]) = v;
    } else if (bid < 10240) {
        const int t2 = bid - 6144, which = t2 >> 10, local = t2 & 1023;
        const float* W = which == 0 ? Wq : (which == 1 ? Wk : (which == 2 ? Wv : Wo));
        short* WT = which == 0 ? WqT : (which == 1 ? WkT : (which == 2 ? WvT : WoT));
        float (*t)[33] = reinterpret_cast<float(*)[33]>(sm);
        const int rb = (local >> 5) * 32, cb = (local & 31) * 32;
        const int tr = tid >> 3, tc = (tid & 7) * 4;
        const float4 v = *reinterpret_cast<const float4*>(&W[(long)(rb + tr) * 1024 + cb + tc]);
        t[tr][tc + 0] = v.x; t[tr][tc + 1] = v.y; t[tr][tc + 2] = v.z; t[tr][tc + 3] = v.w;
        __syncthreads();
        short4 o;
        o.x = f2bf(t[tc + 0][tr]); o.y = f2bf(t[tc + 1][tr]);
        o.z = f2bf(t[tc + 2][tr]); o.w = f2bf(t[tc + 3][tr]);
        *reinterpret_cast<short4*>(&WT[(long)(cb + tr) * 1024 + rb + tc]) = o;
    } else {
        const long base = (long)(bid - 10240) * 8192;
#pragma unroll
        for (int i = 0; i < 8; ++i)
            *reinterpret_cast<int4*>(&sm[i * 1024 + tid * 4]) =
                *reinterpret_cast<const int4*>(&mask[base + i * 1024 + tid * 4]);
        __syncthreads();
        unsigned wv = 0;
#pragma unroll
        for (int j = 0; j < 32; ++j) wv |= (sm[tid * 32 + j] != 0 ? 1u : 0u) << j;
        mb[base / 32 + tid] = wv;
    }
}

// ---------------------------------------------------------------------------
// Fused QKV projection GEMM (z = 0:Q, 1:K, 2:V). 128x128 tile, BK=64, gll.
__global__ __launch_bounds__(256) void k_gemm_qkv(
    const short* __restrict__ A0, const short* __restrict__ A1, const short* __restrict__ A2,
    const short* __restrict__ B0, const short* __restrict__ B1, const short* __restrict__ B2,
    const float* __restrict__ b0, const float* __restrict__ b1, const float* __restrict__ b2,
    short* __restrict__ o0, short* __restrict__ o1, short* __restrict__ o2)
{
    __shared__ short As[128 * 64];
    __shared__ short Bs[128 * 64];
    const int z = blockIdx.z;
    const short* A = z == 0 ? A0 : (z == 1 ? A1 : A2);
    const short* BT = z == 0 ? B0 : (z == 1 ? B1 : B2);
    const float* bias = z == 0 ? b0 : (z == 1 ? b1 : b2);
    short* outp = z == 0 ? o0 : (z == 1 ? o1 : o2);
    const float scale = z == 0 ? QSCALE : 1.0f;

    const int tid = threadIdx.x, w = tid >> 6, lane = tid & 63;
    const int lr = lane & 15, lg = lane >> 4;
    const int rowbase = blockIdx.y * 128, colbase = blockIdx.x * 128;
    const int wr = (w >> 1) * 64, wc = (w & 1) * 64;
    const int srow = lane >> 3, sc_ = (lane & 7) ^ srow;

    f32x4 acc[4][4] = {};

    for (int kb = 0; kb < 1024; kb += 64) {
#pragma unroll
        for (int ii = 0; ii < 4; ++ii) {
            const int rl = w * 32 + ii * 8 + srow;
            gll16(A + (long)(rowbase + rl) * 1024 + kb + sc_ * 8, &As[(w * 32 + ii * 8) * 64]);
            gll16(BT + (long)(colbase + rl) * 1024 + kb + sc_ * 8, &Bs[(w * 32 + ii * 8) * 64]);
        }
        __syncthreads();
#pragma unroll
        for (int ks = 0; ks < 2; ++ks) {
            bf16x8 a[4], bq[4];
#pragma unroll
            for (int m = 0; m < 4; ++m) {
                const int r = wr + m * 16 + lr;
                a[m] = *reinterpret_cast<const bf16x8*>(&As[r * 64 + (((ks * 4 + lg) ^ (r & 7)) << 3)]);
            }
#pragma unroll
            for (int n = 0; n < 4; ++n) {
                const int r = wc + n * 16 + lr;
                bq[n] = *reinterpret_cast<const bf16x8*>(&Bs[r * 64 + (((ks * 4 + lg) ^ (r & 7)) << 3)]);
            }
#pragma unroll
            for (int m = 0; m < 4; ++m)
#pragma unroll
                for (int n = 0; n < 4; ++n)
                    acc[m][n] = __builtin_amdgcn_mfma_f32_16x16x32_bf16(a[m], bq[n], acc[m][n], 0, 0, 0);
        }
        __syncthreads();
    }

#pragma unroll
    for (int m = 0; m < 4; ++m) {
#pragma unroll
        for (int n = 0; n < 4; ++n) {
            const int C = colbase + wc + n * 16 + lr;
            const float bv = bias[C];
#pragma unroll
            for (int rr = 0; rr < 4; ++rr) {
                const int R = rowbase + wr + m * 16 + lg * 4 + rr;
                const float val = (acc[m][n][rr] + bv) * scale;
                const int b = R >> 11, s = R & 2047, h = C >> 6, dh = C & 63;
                if (z != 2)
                    outp[(((long)(b * 16 + h) * 2048 + s) << 6) + dh] = f2bf(val);
                else
                    outp[(((long)(b * 16 + h) * 64 + dh) << 11) + s] = f2bf(val);
            }
        }
    }
}

// ---------------------------------------------------------------------------
// Out-projection GEMM: f32 out = A*WoT + bias + resid
__global__ __launch_bounds__(256) void k_gemm_o(
    const short* __restrict__ A, const short* __restrict__ BT,
    const float* __restrict__ bias, const float* __restrict__ resid,
    float* __restrict__ outp)
{
    __shared__ short As[128 * 64];
    __shared__ short Bs[128 * 64];
    const int tid = threadIdx.x, w = tid >> 6, lane = tid & 63;
    const int lr = lane & 15, lg = lane >> 4;
    const int rowbase = blockIdx.y * 128, colbase = blockIdx.x * 128;
    const int wr = (w >> 1) * 64, wc = (w & 1) * 64;
    const int srow = lane >> 3, sc_ = (lane & 7) ^ srow;

    f32x4 acc[4][4] = {};

    for (int kb = 0; kb < 1024; kb += 64) {
#pragma unroll
        for (int ii = 0; ii < 4; ++ii) {
            const int rl = w * 32 + ii * 8 + srow;
            gll16(A + (long)(rowbase + rl) * 1024 + kb + sc_ * 8, &As[(w * 32 + ii * 8) * 64]);
            gll16(BT + (long)(colbase + rl) * 1024 + kb + sc_ * 8, &Bs[(w * 32 + ii * 8) * 64]);
        }
        __syncthreads();
#pragma unroll
        for (int ks = 0; ks < 2; ++ks) {
            bf16x8 a[4], bq[4];
#pragma unroll
            for (int m = 0; m < 4; ++m) {
                const int r = wr + m * 16 + lr;
                a[m] = *reinterpret_cast<const bf16x8*>(&As[r * 64 + (((ks * 4 + lg) ^ (r & 7)) << 3)]);
            }
#pragma unroll
            for (int n = 0; n < 4; ++n) {
                const int r = wc + n * 16 + lr;
                bq[n] = *reinterpret_cast<const bf16x8*>(&Bs[r * 64 + (((ks * 4 + lg) ^ (r & 7)) << 3)]);
            }
#pragma unroll
            for (int m = 0; m < 4; ++m)
#pragma unroll
                for (int n = 0; n < 4; ++n)
                    acc[m][n] = __builtin_amdgcn_mfma_f32_16x16x32_bf16(a[m], bq[n], acc[m][n], 0, 0, 0);
        }
        __syncthreads();
    }

#pragma unroll
    for (int m = 0; m < 4; ++m) {
#pragma unroll
        for (int n = 0; n < 4; ++n) {
            const int C = colbase + wc + n * 16 + lr;
            const float bv = bias[C];
#pragma unroll
            for (int rr = 0; rr < 4; ++rr) {
                const int R = rowbase + wr + m * 16 + lg * 4 + rr;
                const long idx = (long)R * 1024 + C;
                outp[idx] = acc[m][n][rr] + bv + resid[idx];
            }
        }
    }
}

// ---------------------------------------------------------------------------
// Attention. Block = 64 q-rows (4 waves x 16 rows). Log2-domain softmax.
// Pass 1: QK^T only, per-lane online (m,l) in 16 independent accumulators
//         (no cross-lane ops, no V, no stores) -> C[row] = m + log2(l).
// Pass 2: QK^T recompute, p = exp2(s - C); Ps transpose -> coalesced float4
//         attn stores + PV MFMA. Counted vmcnt keeps stores + K-prefetch in
//         flight across every barrier (K 2-ahead/3-buf, V 1-ahead/2-buf).
__global__ __launch_bounds__(256, 3) void k_attn(
    const short* __restrict__ qh, const short* __restrict__ kh,
    const short* __restrict__ vt, const unsigned* __restrict__ mbits,
    float* __restrict__ attn_out, short* __restrict__ ctxb)
{
    const int g = blockIdx.x, xcd = g & 7, u = g >> 3;
    const int bh = u >> 2, qt = xcd * 4 + (u & 3);
    const int b = bh >> 4;
    const int tid = threadIdx.x, w = tid >> 6, lane = tid & 63;
    const int lr = lane & 15, lg = lane >> 4;
    const int irow = qt * 64 + w * 16;
    const long arow = (long)bh * 2048 + irow;

    __shared__ short Ks[3][64 * 64];
    __shared__ short Vs[2][64 * 64];
    __shared__ short Ps[4][16 * 72];

    const short* qhp = qh + arow * 64;
    const short* khp = kh + (long)bh * 131072;
    const short* vtp = vt + (long)bh * 131072;
    const unsigned* mbp = mbits + (long)b * 131072 + (long)irow * 64;

    const bf16x8 aq0 = *reinterpret_cast<const bf16x8*>(&qhp[lr * 64 + lg * 8]);
    const bf16x8 aq1 = *reinterpret_cast<const bf16x8*>(&qhp[lr * 64 + 32 + lg * 8]);
    const int srow = lane >> 3, sc_ = (lane & 7) ^ srow;

    auto stage_k = [&](int buf, int ch) {
#pragma unroll
        for (int ii = 0; ii < 2; ++ii) {
            const int r0 = w * 16 + ii * 8;
            gll16(khp + (long)(ch * 64 + r0 + srow) * 64 + sc_ * 8, &Ks[buf][r0 * 64]);
        }
    };
    auto stage_v = [&](int buf, int ch) {
#pragma unroll
        for (int ii = 0; ii < 2; ++ii) {
            const int r0 = w * 16 + ii * 8;
            gll16(vtp + (long)(r0 + srow) * 2048 + ch * 64 + sc_ * 8, &Vs[buf][r0 * 64]);
        }
    };
    auto kfrag = [&](int buf, int t, int ks) -> bf16x8 {
        const int r = t * 16 + lr;
        return *reinterpret_cast<const bf16x8*>(&Ks[buf][r * 64 + (((ks * 4 + lg) ^ (r & 7)) << 3)]);
    };
    auto vfrag = [&](int buf, int gi, int ks) -> bf16x8 {
        const int r = gi * 16 + lr;
        return *reinterpret_cast<const bf16x8*>(&Vs[buf][r * 64 + (((ks * 4 + lg) ^ (r & 7)) << 3)]);
    };

    // =============== pass 1: QK^T + per-lane online (m,l) ===============
    float m[4][4], l[4][4];   // [t][rr], 16 independent accumulators
#pragma unroll
    for (int t = 0; t < 4; ++t)
#pragma unroll
        for (int rr = 0; rr < 4; ++rr) { m[t][rr] = -3.0e38f; l[t][rr] = 0.f; }

    stage_k(0, 0); stage_k(1, 1);
    asm volatile("s_waitcnt vmcnt(0)" ::: "memory");
    __builtin_amdgcn_s_barrier();
    asm volatile("" ::: "memory");

    for (int ch = 0; ch < 32; ++ch) {
        const int cur = ch % 3;
        unsigned mw[4][2];
#pragma unroll
        for (int rr = 0; rr < 4; ++rr) {
            mw[rr][0] = mbp[(lg * 4 + rr) * 64 + ch * 2];
            mw[rr][1] = mbp[(lg * 4 + rr) * 64 + ch * 2 + 1];
        }
        stage_k((ch + 2) % 3, (ch + 2) & 31);   // 2-ahead, mod-wrapped
#pragma unroll
        for (int t = 0; t < 4; ++t) {
            f32x4 sc = {};
            sc = __builtin_amdgcn_mfma_f32_16x16x32_bf16(aq0, kfrag(cur, t, 0), sc, 0, 0, 0);
            sc = __builtin_amdgcn_mfma_f32_16x16x32_bf16(aq1, kfrag(cur, t, 1), sc, 0, 0, 0);
#pragma unroll
            for (int rr = 0; rr < 4; ++rr) {
                const bool masked = (mw[rr][t >> 1] >> (((t & 1) << 4) + lr)) & 1;
                const float s = masked ? -1e9f : sc[rr];
                const float d = s - m[t][rr];
                const float e = exp2f(-fabsf(d));
                const bool gt = d > 0.f;
                l[t][rr] = gt ? l[t][rr] * e + 1.f : l[t][rr] + e;
                m[t][rr] = gt ? s : m[t][rr];
            }
        }
        asm volatile("s_waitcnt vmcnt(2)" ::: "memory");   // keep 2-ahead K in flight
        __builtin_amdgcn_s_barrier();
        asm volatile("" ::: "memory");
    }

    // merge: in-lane over t, then 16-lane butterfly -> C[rr] = m + log2(l)
    float C[4];
#pragma unroll
    for (int rr = 0; rr < 4; ++rr) {
        float M = fmaxf(fmaxf(m[0][rr], m[1][rr]), fmaxf(m[2][rr], m[3][rr]));
        float L = l[0][rr] * exp2f(m[0][rr] - M) + l[1][rr] * exp2f(m[1][rr] - M) +
                  l[2][rr] * exp2f(m[2][rr] - M) + l[3][rr] * exp2f(m[3][rr] - M);
#pragma unroll
        for (int off = 1; off < 16; off <<= 1) {
            const float Mo = __shfl_xor(M, off, 16);
            const float Lo = __shfl_xor(L, off, 16);
            const float Mn = fmaxf(M, Mo);
            L = L * exp2f(M - Mn) + Lo * exp2f(Mo - Mn);
            M = Mn;
        }
        C[rr] = M + log2f(L);
    }

    // =============== pass 2: p = exp2(s - C); attn store + PV ===============
    f32x4 acc[4] = {};
    stage_v(0, 0); stage_k(0, 0); stage_k(1, 1);
    asm volatile("s_waitcnt vmcnt(0)" ::: "memory");
    __builtin_amdgcn_s_barrier();
    asm volatile("" ::: "memory");

    for (int ch = 0; ch < 32; ++ch) {
        const int cur = ch % 3;
        unsigned mw[4][2];
#pragma unroll
        for (int rr = 0; rr < 4; ++rr) {
            mw[rr][0] = mbp[(lg * 4 + rr) * 64 + ch * 2];
            mw[rr][1] = mbp[(lg * 4 + rr) * 64 + ch * 2 + 1];
        }
        stage_v((ch + 1) & 1, (ch + 1) & 31);   // 1-ahead (issued before K!)
        stage_k((ch + 2) % 3, (ch + 2) & 31);   // 2-ahead

#pragma unroll
        for (int t = 0; t < 4; ++t) {
            f32x4 sc = {};
            sc = __builtin_amdgcn_mfma_f32_16x16x32_bf16(aq0, kfrag(cur, t, 0), sc, 0, 0, 0);
            sc = __builtin_amdgcn_mfma_f32_16x16x32_bf16(aq1, kfrag(cur, t, 1), sc, 0, 0, 0);
#pragma unroll
            for (int rr = 0; rr < 4; ++rr) {
                const bool masked = (mw[rr][t >> 1] >> (((t & 1) << 4) + lr)) & 1;
                const float s = masked ? -1e9f : sc[rr];
                const float p = exp2f(s - C[rr]);
                Ps[w][(lg * 4 + rr) * 72 + t * 16 + lr] = f2bf(p);
            }
        }
        // coalesced attn writeout: 4 instrs x (4 rows x 256B)
#pragma unroll
        for (int i2 = 0; i2 < 4; ++i2) {
            const int r = i2 * 4 + lg;
            const short4 p4 = *reinterpret_cast<const short4*>(&Ps[w][r * 72 + lr * 4]);
            float4 o;
            o.x = bf2f(p4.x); o.y = bf2f(p4.y); o.z = bf2f(p4.z); o.w = bf2f(p4.w);
            *reinterpret_cast<float4*>(&attn_out[(arow + r) * 2048 + ch * 64 + lr * 4]) = o;
        }
        // PV (normalized p)
        const bf16x8 pa0 = *reinterpret_cast<const bf16x8*>(&Ps[w][lr * 72 + lg * 8]);
        const bf16x8 pa1 = *reinterpret_cast<const bf16x8*>(&Ps[w][lr * 72 + 32 + lg * 8]);
#pragma unroll
        for (int gi = 0; gi < 4; ++gi) {
            acc[gi] = __builtin_amdgcn_mfma_f32_16x16x32_bf16(pa0, vfrag(ch & 1, gi, 0), acc[gi], 0, 0, 0);
            acc[gi] = __builtin_amdgcn_mfma_f32_16x16x32_bf16(pa1, vfrag(ch & 1, gi, 1), acc[gi], 0, 0, 0);
        }
        // retire V_{ch+1} (needed next iter); keep K 2-ahead (2) + stores (4)
        asm volatile("s_waitcnt vmcnt(6)" ::: "memory");
        __builtin_amdgcn_s_barrier();
        asm volatile("" ::: "memory");
    }

    // ctx writeout (already normalized)
#pragma unroll
    for (int gi = 0; gi < 4; ++gi)
#pragma unroll
        for (int rr = 0; rr < 4; ++rr)
            ctxb[(arow + lg * 4 + rr) * 64 + gi * 16 + lr] = f2bf(acc[gi][rr]);
}

// ---------------------------------------------------------------------------
__global__ __launch_bounds__(256) void k_ln(const float* __restrict__ x,
    const float* __restrict__ gamma, const float* __restrict__ beta,
    float* __restrict__ out)
{
    __shared__ float red[8];
    const int r = blockIdx.x, tid = threadIdx.x;
    const float4 v = reinterpret_cast<const float4*>(x + (long)r * 1024)[tid];
    float s = v.x + v.y + v.z + v.w;
    float q2 = v.x * v.x + v.y * v.y + v.z * v.z + v.w * v.w;
#pragma unroll
    for (int off = 32; off; off >>= 1) {
        s += __shfl_xor(s, off, 64);
        q2 += __shfl_xor(q2, off, 64);
    }
    if ((tid & 63) == 0) { red[(tid >> 6) * 2] = s; red[(tid >> 6) * 2 + 1] = q2; }
    __syncthreads();
    s = red[0] + red[2] + red[4] + red[6];
    q2 = red[1] + red[3] + red[5] + red[7];
    const float mu = s * (1.0f / 1024.0f);
    const float var = q2 * (1.0f / 1024.0f) - mu * mu;
    const float rs = rsqrtf(var + 1e-5f);
    const float4 gm = reinterpret_cast<const float4*>(gamma)[tid];
    const float4 bb = reinterpret_cast<const float4*>(beta)[tid];
    float4 o;
    o.x = (v.x - mu) * rs * gm.x + bb.x;
    o.y = (v.y - mu) * rs * gm.y + bb.y;
    o.z = (v.z - mu) * rs * gm.z + bb.z;
    o.w = (v.w - mu) * rs * gm.w + bb.w;
    reinterpret_cast<float4*>(out + (long)r * 1024)[tid] = o;
}

// ---------------------------------------------------------------------------
extern "C" void kernel_launch(void* const* d_in, const int* in_sizes, int n_in,
                              void* d_out, int out_size, void* d_ws, size_t ws_size,
                              hipStream_t stream)
{
    const float* qin  = (const float*)d_in[0];
    const float* kin  = (const float*)d_in[1];
    const float* vin  = (const float*)d_in[2];
    const int*   mask = (const int*)d_in[3];
    const float* Wq = (const float*)d_in[4];
    const float* bq = (const float*)d_in[5];
    const float* Wk = (const float*)d_in[6];
    const float* bk = (const float*)d_in[7];
    const float* Wv = (const float*)d_in[8];
    const float* bv = (const float*)d_in[9];
    const float* Wo = (const float*)d_in[10];
    const float* bo = (const float*)d_in[11];
    const float* gamma = (const float*)d_in[12];
    const float* beta  = (const float*)d_in[13];

    char* ws = (char*)d_ws;
    short* WqT = (short*)(ws + (0ul  << 20));
    short* WkT = (short*)(ws + (2ul  << 20));
    short* WvT = (short*)(ws + (4ul  << 20));
    short* WoT = (short*)(ws + (6ul  << 20));
    short* qbf = (short*)(ws + (8ul  << 20));   // dead after projections; reused by xb
    short* kbf = (short*)(ws + (16ul << 20));   // dead after projections; reused by xb
    short* vbf = (short*)(ws + (24ul << 20));
    short* qh  = (short*)(ws + (32ul << 20));
    short* khb = (short*)(ws + (40ul << 20));
    short* vtb = (short*)(ws + (48ul << 20));
    unsigned* mb = (unsigned*)(ws + (56ul << 20));
    short* ctxb = (short*)(ws + (57ul << 20));  // 8 MB
    float* xb   = (float*)(ws + (8ul  << 20));  // 16 MB, overlaps dead qbf/kbf

    float* outLN = (float*)d_out;
    float* attnO = (float*)d_out + 4194304;

    const dim3 blk(256);
    k_prep<<<dim3(11264), blk, 0, stream>>>(qin, kin, vin, qbf, kbf, vbf,
                                            Wq, Wk, Wv, Wo, WqT, WkT, WvT, WoT, mask, mb);
    k_gemm_qkv<<<dim3(8, 32, 3), blk, 0, stream>>>(qbf, kbf, vbf, WqT, WkT, WvT,
                                                   bq, bk, bv, qh, khb, vtb);
    k_attn<<<dim3(1024), blk, 0, stream>>>(qh, khb, vtb, mb, attnO, ctxb);
    k_gemm_o<<<dim3(8, 32), blk, 0, stream>>>(ctxb, WoT, bo, qin, xb);
    k_ln<<<dim3(4096), blk, 0, stream>>>(xb, gamma, beta, outLN);
}